// Round 4
// baseline (10640.695 us; speedup 1.0000x reference)
//
#include <hip/hip_runtime.h>
#include <hip/hip_fp16.h>

#define CC   184
#define HLEN 24
#define PLEN 24
#define SEQ  48
#define DD   15
#define HB   32
#define BB   512

__device__ __forceinline__ float sigm(float x)  { return 1.0f / (1.0f + __expf(-x)); }
__device__ __forceinline__ float tanhx(float x) { return 1.0f - 2.0f / (1.0f + __expf(2.0f * x)); }

__global__ __launch_bounds__(256, 2) void bilstm_kernel(
    const float* __restrict__ rain_hist,
    const float* __restrict__ feature,
    const float* __restrict__ h0,
    const float* __restrict__ c0,
    const float* __restrict__ W_mlp,
    const float* __restrict__ b_mlp,
    const float* __restrict__ Wih_g,
    const float* __restrict__ Whh_g,
    const float* __restrict__ b_ih_g,
    const float* __restrict__ b_hh_g,
    const float* __restrict__ Wih0,
    const float* __restrict__ Whh0,
    const float* __restrict__ b0,
    const float* __restrict__ Wih1,
    const float* __restrict__ Whh1,
    const float* __restrict__ b1,
    const float* __restrict__ W_fc,
    const float* __restrict__ b_fc,
    float* __restrict__ out)
{
    const int b   = blockIdx.x;
    const int tid = threadIdx.x;

    // LDS (74.2 KB -> 2 blocks/CU)
    __shared__ __align__(16) float xs[CC][16];     // [0]=g [1]=xn [2..14]=feat [15]=0
    __shared__ __align__(16) float y0[CC][64];     // L0 outputs (fwd 0:32, bwd 32:64)
    __shared__ __half               y1f[HB][CC];   // L1 forward outputs (transposed)
    __shared__ __align__(16) float hn_l[4][HB];
    __shared__ __align__(16) float cn_l[4][HB];
    __shared__ __align__(16) float hbuf[2][2][HB]; // ping-pong h exchange
    __shared__ float gx[96];
    __shared__ float gh[4][96];
    __shared__ float ub[16];

    const int l    = tid & 63;          // lane
    const int w    = tid >> 6;          // wave 0..3
    const int dir  = w >> 1;            // 0=fwd, 1=bwd
    const int sub  = w & 1;             // hidden half
    const int g    = l >> 4;            // gate 0=i 1=f 2=g 3=o
    const int kloc = l & 15;
    const int k    = sub * 16 + kloc;   // hidden index 0..31
    const int gb0  = (l >> 4) & 1;
    const int gb1  = (l >> 5) & 1;
    const int row  = g * 32 + k;        // PyTorch gate-row order i,f,g,o

    // ---- init carried state ----
    for (int idx = tid; idx < 4 * HB; idx += 256) {
        int lx = idx >> 5, kx = idx & 31;
        hn_l[lx][kx] = h0[(lx * BB + b) * HB + kx];
        cn_l[lx][kx] = c0[(lx * BB + b) * HB + kx];
    }
    for (int c = tid; c < CC; c += 256) {
        xs[c][0]  = 0.0f;
        xs[c][1]  = rain_hist[(b * HLEN + (HLEN - 1)) * CC + c];
        xs[c][15] = 0.0f;
    }
    __syncthreads();

    float wreg[64];
    float whreg[HB];
    float breg;

    #pragma unroll 1
    for (int t = 0; t < PLEN; ++t) {
        // ---- features ----
        const float* ft = feature + ((size_t)b * SEQ + (HLEN + t)) * CC * 13;
        for (int idx = tid; idx < CC * 13; idx += 256) {
            int c = idx / 13, f = idx - c * 13;
            xs[c][2 + f] = ft[idx];
        }
        __syncthreads();

        // ---- gated graph MLP: g[o] = sigm(b + x1flat . W_mlp[:,o]) ----
        if (tid < CC) {
            float a0 = b_mlp[tid], a1 = 0.f, a2 = 0.f, a3 = 0.f;
            const float* wp = W_mlp + tid;
            #pragma unroll 1
            for (int c = 0; c < CC; ++c) {
                const float4* xq = (const float4*)&xs[c][0];
                float4 q0 = xq[0], q1 = xq[1], q2 = xq[2], q3 = xq[3];
                const float* wc = wp + c * 14 * 184;
                a0 += wc[0 * 184] * q0.y;  a1 += wc[1 * 184] * q0.z;
                a2 += wc[2 * 184] * q0.w;  a3 += wc[3 * 184] * q1.x;
                a0 += wc[4 * 184] * q1.y;  a1 += wc[5 * 184] * q1.z;
                a2 += wc[6 * 184] * q1.w;  a3 += wc[7 * 184] * q2.x;
                a0 += wc[8 * 184] * q2.y;  a1 += wc[9 * 184] * q2.z;
                a2 += wc[10 * 184] * q2.w; a3 += wc[11 * 184] * q3.x;
                a0 += wc[12 * 184] * q3.y; a1 += wc[13 * 184] * q3.z;
            }
            xs[tid][0] = sigm((a0 + a1) + (a2 + a3));
        }
        __syncthreads();

        // ---- u = mean over cities of [g, xn, feat] ----
        if (tid < DD) {
            float a = 0.f;
            #pragma unroll 4
            for (int c = 0; c < CC; ++c) a += xs[c][tid];
            ub[tid] = a * (1.0f / CC);
        }
        __syncthreads();

        // ---- GRU ----
        if (tid < 96) {
            float a = b_ih_g[tid];
            #pragma unroll
            for (int m = 0; m < DD; ++m) a += ub[m] * Wih_g[m * 96 + tid];
            gx[tid] = a;
        }
        for (int idx = tid; idx < 4 * 96; idx += 256) {
            int lx = idx / 96, j = idx - lx * 96;
            float a = b_hh_g[j];
            #pragma unroll
            for (int m = 0; m < HB; ++m) a += hn_l[lx][m] * Whh_g[m * 96 + j];
            gh[lx][j] = a;
        }
        __syncthreads();
        if (tid < 128) {
            int lx = tid >> 5, kx = tid & 31;
            float r = sigm(gx[kx] + gh[lx][kx]);
            float z = sigm(gx[HB + kx] + gh[lx][HB + kx]);
            float n = tanhx(gx[2 * HB + kx] + r * gh[lx][2 * HB + kx]);
            hn_l[lx][kx] = (1.0f - z) * n + z * hn_l[lx][kx];
        }
        __syncthreads();

        // ==== BiLSTM layer 0 over cities ====
        {
            const float* Wp = Wih0 + (dir * 128 + row) * DD;
            #pragma unroll
            for (int j = 0; j < DD; ++j) wreg[j] = Wp[j];
            wreg[15] = 0.0f;
            const float* Hp = Whh0 + (dir * 128 + row) * HB;
            #pragma unroll
            for (int m = 0; m < HB; ++m) whreg[m] = Hp[m];
            breg = b0[dir * 128 + row];

            float c_st = cn_l[dir][k];
            float hv = 0.0f;

            // prime x-dot for ci=0
            float xacc;
            {
                const int xc0 = dir ? (CC - 1) : 0;
                const float4* xq = (const float4*)&xs[xc0][0];
                float a0 = 0.f, a1 = 0.f, a2 = 0.f, a3 = 0.f;
                #pragma unroll
                for (int q = 0; q < 4; ++q) {
                    float4 v = xq[q];
                    a0 += v.x * wreg[4 * q];     a1 += v.y * wreg[4 * q + 1];
                    a2 += v.z * wreg[4 * q + 2]; a3 += v.w * wreg[4 * q + 3];
                }
                xacc = (a0 + a1) + (a2 + a3);
            }

            #pragma unroll 1
            for (int ci = 0; ci < CC; ++ci) {
                const float* hsrc = (ci == 0) ? &hn_l[dir][0] : &hbuf[ci & 1][dir][0];
                float a0 = xacc + breg, a1 = 0.f, a2 = 0.f, a3 = 0.f;
                const float4* hq = (const float4*)hsrc;
                #pragma unroll
                for (int q = 0; q < 8; ++q) {
                    float4 v = hq[q];
                    a0 += v.x * whreg[4 * q];     a1 += v.y * whreg[4 * q + 1];
                    a2 += v.z * whreg[4 * q + 2]; a3 += v.w * whreg[4 * q + 3];
                }
                float av  = (a0 + a1) + (a2 + a3);
                float s16 = __shfl_xor(av, 16);
                float s32 = __shfl_xor(av, 32);
                float s48 = __shfl_xor(s16, 32);
                float A0 = gb0 ? s16 : av,  A1 = gb0 ? av  : s16;
                float B0 = gb0 ? s48 : s32, B1 = gb0 ? s32 : s48;
                float iv = gb1 ? B0 : A0, fv = gb1 ? B1 : A1;
                float gv = gb1 ? A0 : B0, ov = gb1 ? A1 : B1;
                c_st = sigm(fv) * c_st + sigm(iv) * tanhx(gv);
                hv   = sigm(ov) * tanhx(c_st);
                const int xc = dir ? (CC - 1 - ci) : ci;
                if (g == 0) {
                    hbuf[(ci + 1) & 1][dir][k] = hv;
                    y0[xc][dir * 32 + k] = hv;
                }
                __syncthreads();
                if (ci + 1 < CC) {
                    const int xcn = dir ? (CC - 2 - ci) : (ci + 1);
                    const float4* xq = (const float4*)&xs[xcn][0];
                    float b0_ = 0.f, b1_ = 0.f, b2_ = 0.f, b3_ = 0.f;
                    #pragma unroll
                    for (int q = 0; q < 4; ++q) {
                        float4 v = xq[q];
                        b0_ += v.x * wreg[4 * q];     b1_ += v.y * wreg[4 * q + 1];
                        b2_ += v.z * wreg[4 * q + 2]; b3_ += v.w * wreg[4 * q + 3];
                    }
                    xacc = (b0_ + b1_) + (b2_ + b3_);
                }
            }
            if (g == 0) { hn_l[dir][k] = hv; cn_l[dir][k] = c_st; }
        }
        __syncthreads();

        // ==== BiLSTM layer 1 over y0 ====
        {
            const float* Wp = Wih1 + (dir * 128 + row) * 64;
            #pragma unroll
            for (int j = 0; j < 64; ++j) wreg[j] = Wp[j];
            const float* Hp = Whh1 + (dir * 128 + row) * HB;
            #pragma unroll
            for (int m = 0; m < HB; ++m) whreg[m] = Hp[m];
            breg = b1[dir * 128 + row];

            float c_st = cn_l[2 + dir][k];
            float hv = 0.0f;

            float xacc;
            {
                const int xc0 = dir ? (CC - 1) : 0;
                const float4* xq = (const float4*)&y0[xc0][0];
                float a0 = 0.f, a1 = 0.f, a2 = 0.f, a3 = 0.f;
                #pragma unroll
                for (int q = 0; q < 16; ++q) {
                    float4 v = xq[q];
                    a0 += v.x * wreg[4 * q];     a1 += v.y * wreg[4 * q + 1];
                    a2 += v.z * wreg[4 * q + 2]; a3 += v.w * wreg[4 * q + 3];
                }
                xacc = (a0 + a1) + (a2 + a3);
            }

            #pragma unroll 1
            for (int ci = 0; ci < CC; ++ci) {
                const float* hsrc = (ci == 0) ? &hn_l[2 + dir][0] : &hbuf[ci & 1][dir][0];
                float a0 = xacc + breg, a1 = 0.f, a2 = 0.f, a3 = 0.f;
                const float4* hq = (const float4*)hsrc;
                #pragma unroll
                for (int q = 0; q < 8; ++q) {
                    float4 v = hq[q];
                    a0 += v.x * whreg[4 * q];     a1 += v.y * whreg[4 * q + 1];
                    a2 += v.z * whreg[4 * q + 2]; a3 += v.w * whreg[4 * q + 3];
                }
                float av  = (a0 + a1) + (a2 + a3);
                float s16 = __shfl_xor(av, 16);
                float s32 = __shfl_xor(av, 32);
                float s48 = __shfl_xor(s16, 32);
                float A0 = gb0 ? s16 : av,  A1 = gb0 ? av  : s16;
                float B0 = gb0 ? s48 : s32, B1 = gb0 ? s32 : s48;
                float iv = gb1 ? B0 : A0, fv = gb1 ? B1 : A1;
                float gv = gb1 ? A0 : B0, ov = gb1 ? A1 : B1;
                c_st = sigm(fv) * c_st + sigm(iv) * tanhx(gv);
                hv   = sigm(ov) * tanhx(c_st);
                if (g == 0) {
                    hbuf[(ci + 1) & 1][dir][k] = hv;
                    if (dir == 0) y1f[k][ci] = __float2half(hv);
                }
                __syncthreads();
                if (ci + 1 < CC) {
                    const int xcn = dir ? (CC - 2 - ci) : (ci + 1);
                    const float4* xq = (const float4*)&y0[xcn][0];
                    float b0_ = 0.f, b1_ = 0.f, b2_ = 0.f, b3_ = 0.f;
                    #pragma unroll
                    for (int q = 0; q < 16; ++q) {
                        float4 v = xq[q];
                        b0_ += v.x * wreg[4 * q];     b1_ += v.y * wreg[4 * q + 1];
                        b2_ += v.z * wreg[4 * q + 2]; b3_ += v.w * wreg[4 * q + 3];
                    }
                    xacc = (b0_ + b1_) + (b2_ + b3_);
                }
            }
            if (g == 0) { hn_l[2 + dir][k] = hv; cn_l[2 + dir][k] = c_st; }
        }
        __syncthreads();

        // ---- FC head: xn[c] = y1_fwd[c] . W_fc + b_fc ----
        if (tid < CC) {
            float acc = b_fc[0];
            #pragma unroll
            for (int m = 0; m < HB; ++m)
                acc += __half2float(y1f[m][tid]) * W_fc[m];
            out[((size_t)b * PLEN + t) * CC + tid] = acc;
            xs[tid][1] = acc;
        }
        __syncthreads();
    }
}

extern "C" void kernel_launch(void* const* d_in, const int* in_sizes, int n_in,
                              void* d_out, int out_size, void* d_ws, size_t ws_size,
                              hipStream_t stream) {
    const float* rain_hist = (const float*)d_in[0];
    const float* feature   = (const float*)d_in[1];
    const float* h0        = (const float*)d_in[2];
    const float* c0        = (const float*)d_in[3];
    const float* W_mlp     = (const float*)d_in[4];
    const float* b_mlp     = (const float*)d_in[5];
    const float* Wih_g     = (const float*)d_in[6];
    const float* Whh_g     = (const float*)d_in[7];
    const float* b_ih_g    = (const float*)d_in[8];
    const float* b_hh_g    = (const float*)d_in[9];
    const float* Wih0      = (const float*)d_in[10];
    const float* Whh0      = (const float*)d_in[11];
    const float* b0        = (const float*)d_in[12];
    const float* Wih1      = (const float*)d_in[13];
    const float* Whh1      = (const float*)d_in[14];
    const float* b1        = (const float*)d_in[15];
    const float* W_fc      = (const float*)d_in[16];
    const float* b_fc      = (const float*)d_in[17];
    float* out = (float*)d_out;

    bilstm_kernel<<<dim3(BB), dim3(256), 0, stream>>>(
        rain_hist, feature, h0, c0, W_mlp, b_mlp, Wih_g, Whh_g, b_ih_g, b_hh_g,
        Wih0, Whh0, b0, Wih1, Whh1, b1, W_fc, b_fc, out);
}